// Round 1
// 343.481 us; speedup vs baseline: 1.0091x; 1.0091x over previous
//
#include <hip/hip_runtime.h>

#define NB 2
#define NPTS 8192
#define NQ 4096
#define MTOT 8192      // NB*NQ
#define SP 16
#define SD 32
#define CIN 32
#define CP 32
#define CF 64
#define NROI 128       // NB*64
#define RADIUS_C 0.8f
#define MIN_R_C 0.01f
#define DIV_COEF_C 10.0f

// ---------------- device-global scratch (fully rewritten every call) -------
__device__ int   g_idx_p[MTOT * SP];
__device__ int   g_empty_p[MTOT];
__device__ int   g_idx_d[MTOT * SD];
__device__ int   g_empty_d[MTOT];
__device__ float g_psT[CF * 2048];                // transposed: [ch][block]
__device__ float g_pqT[CF * 2048];
__device__ float g_bnscale[4][CF];                // 0=p0 1=p1 2=f0 3=f1
__device__ float g_bnshift[4][CF];
__device__ float g_pdot[MTOT];
__device__ float g_rroi[NROI];

// ---------------- new_xyz output is rois flattened -------------------------
__global__ void copy_xyz_kernel(const float* __restrict__ rois, float* __restrict__ out) {
    int i = blockIdx.x * 256 + threadIdx.x;
    if (i < MTOT * 3) out[i] = rois[i];
}

// ---------------- ball query: one wave per query, index-ordered scan -------
template <int NS>
__launch_bounds__(1024, 4)
__global__ void bq_kernel(const float* __restrict__ xyz, const float* __restrict__ newxyz) {
    __shared__ float l_xyz[NPTS * 3];   // 96 KB
    int tid = threadIdx.x;
    int qbase = blockIdx.x * 32;        // 32 queries per block, all same batch
    int b = qbase >> 12;
    const float4* xb4 = (const float4*)(xyz + (size_t)b * NPTS * 3);
    float4* l4 = (float4*)l_xyz;
    for (int v = tid; v < NPTS * 3 / 4; v += 1024) l4[v] = xb4[v];
    __syncthreads();

    int* idx_out   = (NS == SP) ? g_idx_p   : g_idx_d;
    int* empty_out = (NS == SP) ? g_empty_p : g_empty_d;

    int wave = tid >> 6, lane = tid & 63;
    for (int i = 0; i < 2; ++i) {
        int q = qbase + wave * 2 + i;
        float qx = newxyz[q * 3 + 0], qy = newxyz[q * 3 + 1], qz = newxyz[q * 3 + 2];
        float r = (NS == SP) ? RADIUS_C : g_rroi[q >> 6];
        float r2 = r * r;
        int cnt = 0, first_idx = 0;
        float cx = l_xyz[3 * lane + 0];
        float cy = l_xyz[3 * lane + 1];
        float cz = l_xyz[3 * lane + 2];
        for (int g = 0; g < NPTS / 64 && cnt < NS; ++g) {
            int pn = (((g + 1) & 127) << 6) + lane;
            float nx = l_xyz[3 * pn + 0];
            float ny = l_xyz[3 * pn + 1];
            float nz = l_xyz[3 * pn + 2];
            float dx = qx - cx, dy = qy - cy, dz = qz - cz;
            float d2 = dx * dx + dy * dy + dz * dz;
            bool valid = d2 < r2;
            unsigned long long mask = __ballot(valid);
            if (cnt == 0 && mask) first_idx = (g << 6) + (int)__builtin_ctzll(mask);
            int pos = cnt + __popcll(mask & ((1ull << lane) - 1ull));
            if (valid && pos < NS) idx_out[q * NS + pos] = (g << 6) + lane;
            cnt += __popcll(mask);
            cx = nx; cy = ny; cz = nz;
        }
        if (cnt == 0) {
            if (lane < NS) idx_out[q * NS + lane] = 0;
            if (lane == 0) empty_out[q] = 1;
        } else {
            int filled = cnt < NS ? cnt : NS;
            if (lane >= filled && lane < NS) idx_out[q * NS + lane] = first_idx;
            if (lane == 0) empty_out[q] = 0;
        }
    }
}

// ============ fused recompute MLP: no materialized activations =============
// MODE 0: gather -> L0 -> per-channel stats partials (for BN0)
// MODE 1: gather -> L0 -> BN0+ReLU -> L1 -> stats partials (for BN1)
// MODE 2: gather -> L0 -> BN0+ReLU -> L1 -> BN1+ReLU [-> *w] -> pool -> out
// block = 128 threads (2 waves), one row per thread.
// LDS: single 18.5 KB buffer reused as {gather rows [128][37]} ->
//      {h rows [128][33], per 32-ch half-chunk} -> {stats/pool transpose [64][CH+2]}
template <int NS, int CH, int MODE>
__launch_bounds__(128, (CH == 64 && MODE != 0) ? 3 : 4)
__global__ void fused_mlp_kernel(const float* __restrict__ xyz, const float* __restrict__ feats,
                                 const float* __restrict__ newxyz,
                                 const float* __restrict__ W0, const float* __restrict__ W1,
                                 const float* __restrict__ fcw, const float* __restrict__ td,
                                 float* __restrict__ out, int bn0, int bn1) {
    constexpr int GSTR = 37;        // gather row stride (35 used), 2-way banks: free
    constexpr int HSTR = 33;        // h row stride (32 used), conflict-free
    constexpr int SST  = CH + 2;    // stats/pool transpose stride, 2-way banks: free
    __shared__ float buf[128 * GSTR];   // 18944 B, all phases overlay here
    __shared__ float ls[128], lq[128];

    int tid = threadIdx.x;
    int row = blockIdx.x * 128 + tid;
    int q = row / NS;
    int b = q >> 12;
    const int* idx_arr = (NS == SP) ? g_idx_p : g_idx_d;
    const int* emp_arr = (NS == SP) ? g_empty_p : g_empty_d;

    float w_sig = 0.f;              // deform-branch sigmoid weight (MODE 2, CH==CF)
    {
        float* dst = &buf[tid * GSTR];
        if (emp_arr[q]) {
#pragma unroll
            for (int c = 0; c < 35; ++c) dst[c] = 0.f;
        } else {
            int idx = idx_arr[row];
            const float* xp = xyz + (size_t)b * NPTS * 3 + idx * 3;
            float dx = xp[0] - newxyz[q * 3 + 0];
            float dy = xp[1] - newxyz[q * 3 + 1];
            float dz = xp[2] - newxyz[q * 3 + 2];
            dst[0] = dx; dst[1] = dy; dst[2] = dz;
            const float4* fp = (const float4*)(feats + (size_t)b * NPTS * CIN + (size_t)idx * CIN);
#pragma unroll
            for (int j = 0; j < 8; ++j) {
                float4 v = fp[j];
                dst[3 + 4 * j + 0] = v.x; dst[3 + 4 * j + 1] = v.y;
                dst[3 + 4 * j + 2] = v.z; dst[3 + 4 * j + 3] = v.w;
            }
            if (MODE == 2 && CH == CF) {
                float dist = sqrtf(dx * dx + dy * dy + dz * dz);
                float rq = g_rroi[q >> 6];
                w_sig = 1.f / (1.f + expf(-(rq - dist) / td[0]));
            }
        }
    }

    // ---- layer 0: each thread reads only its own LDS row (no barrier) ----
    float acc[CH];
#pragma unroll
    for (int ch = 0; ch < CH; ++ch) acc[ch] = 0.f;
    {
        const float* inrow = &buf[tid * GSTR];
        for (int c = 0; c < 35; ++c) {
            float h = inrow[c];
#pragma unroll
            for (int ch = 0; ch < CH; ++ch) acc[ch] = fmaf(h, W0[c * CH + ch], acc[ch]);
        }
    }

    // ---- per-channel block stats via chunked LDS transpose (64 rows/pass) ----
    auto block_stats = [&](float (&sv)[CH]) {
        float sum = 0.f, sq = 0.f;
#pragma unroll
        for (int p = 0; p < 2; ++p) {
            __syncthreads();
            if ((tid >> 6) == p) {
                float* srow = &buf[(tid & 63) * SST];
#pragma unroll
                for (int ch = 0; ch < CH; ++ch) srow[ch] = sv[ch];
            }
            __syncthreads();
            if (CH == 64) {
                int ch = tid & 63, rg = tid >> 6;
                for (int r = 0; r < 32; ++r) {
                    float v = buf[(rg * 32 + r) * SST + ch]; sum += v; sq += v * v;
                }
            } else {
                int ch = tid & 31, rg = tid >> 5;
                for (int r = 0; r < 16; ++r) {
                    float v = buf[(rg * 16 + r) * SST + ch]; sum += v; sq += v * v;
                }
            }
        }
        ls[tid] = sum; lq[tid] = sq;
        __syncthreads();
        if (CH == 64) {
            if (tid < 64) {
                g_psT[tid * 2048 + blockIdx.x] = ls[tid] + ls[64 + tid];
                g_pqT[tid * 2048 + blockIdx.x] = lq[tid] + lq[64 + tid];
            }
        } else {
            if (tid < 32) {
                g_psT[tid * 2048 + blockIdx.x] = ls[tid] + ls[32 + tid] + ls[64 + tid] + ls[96 + tid];
                g_pqT[tid * 2048 + blockIdx.x] = lq[tid] + lq[32 + tid] + lq[64 + tid] + lq[96 + tid];
            }
        }
    };

    if constexpr (MODE == 0) {
        block_stats(acc);
    } else {
        // ---- layer 1: h kept in LDS rows (dynamic index without scratch),
        //      processed in 32-channel half-chunks so LDS stays <= 19.5 KB ----
        float acc2[CH];
#pragma unroll
        for (int ch = 0; ch < CH; ++ch) acc2[ch] = 0.f;
        const float* sc0 = g_bnscale[bn0];
        const float* sh0 = g_bnshift[bn0];
#pragma unroll
        for (int hc = 0; hc < CH / 32; ++hc) {
            __syncthreads();            // prior readers of this LDS region done
            float* hrow = &buf[tid * HSTR];
#pragma unroll
            for (int j = 0; j < 32; ++j)
                hrow[j] = fmaxf(fmaf(acc[hc * 32 + j], sc0[hc * 32 + j], sh0[hc * 32 + j]), 0.f);
            // own-row write->read: no barrier needed
            for (int c = 0; c < 32; ++c) {
                float h = hrow[c];
#pragma unroll
                for (int ch = 0; ch < CH; ++ch)
                    acc2[ch] = fmaf(h, W1[(hc * 32 + c) * CH + ch], acc2[ch]);
            }
        }

        if constexpr (MODE == 1) {
            block_stats(acc2);
        } else {
            const float* sc1 = g_bnscale[bn1];
            const float* sh1 = g_bnshift[bn1];
            if constexpr (CH == CF) {
                // deform branch final: v = w * relu(BN1(x1)); max over 32 samples
#pragma unroll
                for (int ch = 0; ch < CH; ++ch)
                    acc2[ch] = w_sig * fmaxf(fmaf(acc2[ch], sc1[ch], sh1[ch]), 0.f);
                int qbase = blockIdx.x * 4;
#pragma unroll
                for (int p = 0; p < 2; ++p) {
                    __syncthreads();
                    if ((tid >> 6) == p) {
                        float* srow = &buf[(tid & 63) * SST];
#pragma unroll
                        for (int ch = 0; ch < CH; ++ch) srow[ch] = acc2[ch];
                    }
                    __syncthreads();
                    int ch = tid & 63, rg = tid >> 6;
                    float m = 0.f;
                    for (int r = 0; r < 32; ++r) m = fmaxf(m, buf[(rg * 32 + r) * SST + ch]);
                    out[MTOT * 3 + (size_t)(qbase + p * 2 + rg) * CF + ch] = m;
                }
            } else {
                // pred branch final: relu(BN1(x1)); max over 16 samples; dot fcw
#pragma unroll
                for (int ch = 0; ch < CH; ++ch)
                    acc2[ch] = fmaxf(fmaf(acc2[ch], sc1[ch], sh1[ch]), 0.f);
                int qbase = blockIdx.x * 8;
#pragma unroll
                for (int p = 0; p < 2; ++p) {
                    __syncthreads();
                    if ((tid >> 6) == p) {
                        float* srow = &buf[(tid & 63) * SST];
#pragma unroll
                        for (int ch = 0; ch < CH; ++ch) srow[ch] = acc2[ch];
                    }
                    __syncthreads();
                    int ch = tid & 31, qh = tid >> 5;
                    int qq = qbase + p * 4 + qh;
                    float m = 0.f;
                    for (int r = 0; r < 16; ++r) m = fmaxf(m, buf[(qh * 16 + r) * SST + ch]);
                    float pd = m * fcw[(qq & 63) * CP + ch];
                    for (int off = 16; off > 0; off >>= 1) pd += __shfl_down(pd, off, 32);
                    if (ch == 0) g_pdot[qq] = pd;
                }
            }
        }
    }
}

// -------- BN stats finalize: one block per channel, coalesced, tree-reduce --
__global__ void finalize_kernel(const float* __restrict__ gamma, const float* __restrict__ beta,
                                float n, int layer, int nblocks) {
    __shared__ double l_s[256], l_q[256];
    int ch = blockIdx.x, tid = threadIdx.x;
    double s = 0, q = 0;
    for (int i = tid; i < nblocks; i += 256) { s += g_psT[ch * 2048 + i]; q += g_pqT[ch * 2048 + i]; }
    l_s[tid] = s; l_q[tid] = q; __syncthreads();
    for (int off = 128; off > 0; off >>= 1) {
        if (tid < off) { l_s[tid] += l_s[tid + off]; l_q[tid] += l_q[tid + off]; }
        __syncthreads();
    }
    if (tid == 0) {
        double mu = l_s[0] / (double)n;
        double var = l_q[0] / (double)n - mu * mu;
        if (var < 0) var = 0;
        double sc = (double)gamma[ch] / sqrt(var + 1e-5);
        g_bnscale[layer][ch] = (float)sc;
        g_bnshift[layer][ch] = (float)((double)beta[ch] - mu * sc);
    }
}

// ---------------- per-roi fc reduce -> deform radius -----------------------
__global__ void roi_r_kernel(const float* __restrict__ roif, const float* __restrict__ fcw,
                             const float* __restrict__ fcb) {
    int tid = threadIdx.x;
    int roi = blockIdx.x * 4 + (tid >> 6);
    int lane = tid & 63;
    float acc = g_pdot[roi * 64 + lane]
              + roif[roi * 128 + lane]      * fcw[2048 + lane]
              + roif[roi * 128 + 64 + lane] * fcw[2048 + 64 + lane];
    for (int off = 32; off > 0; off >>= 1) acc += __shfl_down(acc, off, 64);
    if (lane == 0) {
        float res = acc + fcb[0];
        g_rroi[roi] = fmaxf(res / DIV_COEF_C + RADIUS_C, MIN_R_C);
    }
}

extern "C" void kernel_launch(void* const* d_in, const int* in_sizes, int n_in,
                              void* d_out, int out_size, void* d_ws, size_t ws_size,
                              hipStream_t stream) {
    const float* xyz   = (const float*)d_in[0];
    const float* feats = (const float*)d_in[1];
    const float* rois  = (const float*)d_in[2];
    const float* roif  = (const float*)d_in[3];
    const float* td    = (const float*)d_in[4];
    const float* pw0 = (const float*)d_in[5];
    const float* pg0 = (const float*)d_in[6];
    const float* pb0 = (const float*)d_in[7];
    const float* pw1 = (const float*)d_in[8];
    const float* pg1 = (const float*)d_in[9];
    const float* pb1 = (const float*)d_in[10];
    const float* fw0 = (const float*)d_in[11];
    const float* fg0 = (const float*)d_in[12];
    const float* fb0 = (const float*)d_in[13];
    const float* fw1 = (const float*)d_in[14];
    const float* fg1 = (const float*)d_in[15];
    const float* fb1 = (const float*)d_in[16];
    const float* fcw = (const float*)d_in[17];
    const float* fcb = (const float*)d_in[18];
    float* out = (float*)d_out;

    copy_xyz_kernel<<<96, 256, 0, stream>>>(rois, out);

    // pred branch (16 samples, 32 ch): stats0 -> BN0 -> stats1 -> BN1 -> final
    bq_kernel<SP><<<256, 1024, 0, stream>>>(xyz, rois);
    fused_mlp_kernel<SP, CP, 0><<<1024, 128, 0, stream>>>(xyz, feats, rois, pw0, nullptr, nullptr, nullptr, nullptr, 0, 0);
    finalize_kernel<<<CP, 256, 0, stream>>>(pg0, pb0, (float)(MTOT * SP), 0, 1024);
    fused_mlp_kernel<SP, CP, 1><<<1024, 128, 0, stream>>>(xyz, feats, rois, pw0, pw1, nullptr, nullptr, nullptr, 0, 0);
    finalize_kernel<<<CP, 256, 0, stream>>>(pg1, pb1, (float)(MTOT * SP), 1, 1024);
    fused_mlp_kernel<SP, CP, 2><<<1024, 128, 0, stream>>>(xyz, feats, rois, pw0, pw1, fcw, nullptr, nullptr, 0, 1);
    roi_r_kernel<<<NROI / 4, 256, 0, stream>>>(roif, fcw, fcb);

    // deform branch (32 samples, 64 ch)
    bq_kernel<SD><<<256, 1024, 0, stream>>>(xyz, rois);
    fused_mlp_kernel<SD, CF, 0><<<2048, 128, 0, stream>>>(xyz, feats, rois, fw0, nullptr, nullptr, nullptr, nullptr, 0, 0);
    finalize_kernel<<<CF, 256, 0, stream>>>(fg0, fb0, (float)(MTOT * SD), 2, 2048);
    fused_mlp_kernel<SD, CF, 1><<<2048, 128, 0, stream>>>(xyz, feats, rois, fw0, fw1, nullptr, nullptr, nullptr, 2, 0);
    finalize_kernel<<<CF, 256, 0, stream>>>(fg1, fb1, (float)(MTOT * SD), 3, 2048);
    fused_mlp_kernel<SD, CF, 2><<<2048, 128, 0, stream>>>(xyz, feats, rois, fw0, fw1, nullptr, td, out, 2, 3);
}

// Round 2
// 309.598 us; speedup vs baseline: 1.1196x; 1.1094x over previous
//
#include <hip/hip_runtime.h>

#define NB 2
#define NPTS 8192
#define NQ 4096
#define MTOT 8192      // NB*NQ
#define SP 16
#define SD 32
#define CIN 32
#define CP 32
#define CF 64
#define NROI 128       // NB*64
#define RADIUS_C 0.8f
#define MIN_R_C 0.01f
#define DIV_COEF_C 10.0f

// ---------------- device-global scratch (fully rewritten every call) -------
__device__ int   g_idx_p[MTOT * SP];
__device__ int   g_empty_p[MTOT];
__device__ int   g_idx_d[MTOT * SD];
__device__ int   g_empty_d[MTOT];
__device__ float g_xa[(size_t)MTOT * SD * CF];    // 67 MB generic activation buf
__device__ float g_xb[(size_t)MTOT * SD * CF];    // 67 MB
__device__ float g_psT[CF * 2048];                // transposed: [ch][block]
__device__ float g_pqT[CF * 2048];
__device__ float g_bnscale[4][CF];                // 0=p0 1=p1 2=f0 3=f1
__device__ float g_bnshift[4][CF];
__device__ float g_pdot[MTOT];
__device__ float g_rroi[NROI];

// ---------------- new_xyz output is rois flattened -------------------------
__global__ void copy_xyz_kernel(const float* __restrict__ rois, float* __restrict__ out) {
    int i = blockIdx.x * 256 + threadIdx.x;
    if (i < MTOT * 3) out[i] = rois[i];
}

// ---------------- ball query: one wave per QUERY, no LDS, L2-resident xyz --
// xyz per batch = 96 KB -> L2 hit after first touch; rolling 1-group prefetch
// hides L2 latency; 8 waves/SIMD occupancy (no LDS, low VGPR).
template <int NS>
__launch_bounds__(256, 8)
__global__ void bq_kernel(const float* __restrict__ xyz, const float* __restrict__ newxyz) {
    int lane = threadIdx.x & 63;
    int q = blockIdx.x * 4 + (threadIdx.x >> 6);   // one query per wave
    int b = q >> 12;
    const float* xb = xyz + (size_t)b * NPTS * 3;
    float qx = newxyz[q * 3 + 0], qy = newxyz[q * 3 + 1], qz = newxyz[q * 3 + 2];
    float r = (NS == SP) ? RADIUS_C : g_rroi[q >> 6];
    float r2 = r * r;
    int* idx_out   = (NS == SP) ? g_idx_p   : g_idx_d;
    int* empty_out = (NS == SP) ? g_empty_p : g_empty_d;

    int cnt = 0, first_idx = 0;
    float cx = xb[3 * lane + 0];
    float cy = xb[3 * lane + 1];
    float cz = xb[3 * lane + 2];
    for (int g = 0; g < NPTS / 64 && cnt < NS; ++g) {
        int pn = (((g + 1) & 127) << 6) + lane;    // prefetch next group
        float nx = xb[3 * pn + 0];
        float ny = xb[3 * pn + 1];
        float nz = xb[3 * pn + 2];
        float dx = qx - cx, dy = qy - cy, dz = qz - cz;
        float d2 = dx * dx + dy * dy + dz * dz;
        bool valid = d2 < r2;
        unsigned long long mask = __ballot(valid);
        if (cnt == 0 && mask) first_idx = (g << 6) + (int)__builtin_ctzll(mask);
        int pos = cnt + __popcll(mask & ((1ull << lane) - 1ull));
        if (valid && pos < NS) idx_out[q * NS + pos] = (g << 6) + lane;
        cnt += __popcll(mask);
        cx = nx; cy = ny; cz = nz;
    }
    if (cnt == 0) {
        if (lane < NS) idx_out[q * NS + lane] = 0;
        if (lane == 0) empty_out[q] = 1;
    } else {
        int filled = cnt < NS ? cnt : NS;
        if (lane >= filled && lane < NS) idx_out[q * NS + lane] = first_idx;
        if (lane == 0) empty_out[q] = 0;
    }
}

// ============ 3-pass MLP: materialize fp32 x0/x1 on lean template ==========
// PASS A: gather -> L0 -> store x0 (transposed-coalesced) + stats partials
// PASS B: stream x0 -> BN0+ReLU -> L1 -> store x1 + stats partials
// PASS C: stream x1 -> BN1+ReLU (+sigmoid weight) -> pool -> out
// block = 128 threads (2 waves), LDS <= 19.5 KB -> 8 blocks/CU.

template <int NS, int CH>
__launch_bounds__(128, 4)
__global__ void mlp_passA_kernel(const float* __restrict__ xyz, const float* __restrict__ feats,
                                 const float* __restrict__ newxyz, const float* __restrict__ W0,
                                 float* __restrict__ xout) {
    constexpr int GSTR = 37;        // gather row stride (35 used)
    constexpr int SST  = CH + 2;    // stats/store transpose stride
    __shared__ float buf[128 * GSTR];
    __shared__ float ls[128], lq[128];
    int tid = threadIdx.x;
    int rowbase = blockIdx.x * 128;
    int row = rowbase + tid;
    int q = row / NS, b = q >> 12;
    const int* idx_arr = (NS == SP) ? g_idx_p : g_idx_d;
    const int* emp_arr = (NS == SP) ? g_empty_p : g_empty_d;
    {
        float* dst = &buf[tid * GSTR];
        if (emp_arr[q]) {
#pragma unroll
            for (int c = 0; c < 35; ++c) dst[c] = 0.f;
        } else {
            int idx = idx_arr[row];
            const float* xp = xyz + (size_t)b * NPTS * 3 + idx * 3;
            dst[0] = xp[0] - newxyz[q * 3 + 0];
            dst[1] = xp[1] - newxyz[q * 3 + 1];
            dst[2] = xp[2] - newxyz[q * 3 + 2];
            const float4* fp = (const float4*)(feats + (size_t)b * NPTS * CIN + (size_t)idx * CIN);
#pragma unroll
            for (int j = 0; j < 8; ++j) {
                float4 v = fp[j];
                dst[3 + 4 * j + 0] = v.x; dst[3 + 4 * j + 1] = v.y;
                dst[3 + 4 * j + 2] = v.z; dst[3 + 4 * j + 3] = v.w;
            }
        }
    }
    // L0 from own LDS row (no barrier needed)
    float acc[CH];
#pragma unroll
    for (int ch = 0; ch < CH; ++ch) acc[ch] = 0.f;
    {
        const float* inrow = &buf[tid * GSTR];
        for (int c = 0; c < 35; ++c) {
            float h = inrow[c];
#pragma unroll
            for (int ch = 0; ch < CH; ++ch) acc[ch] = fmaf(h, W0[c * CH + ch], acc[ch]);
        }
    }
    // stats + coalesced store via chunked LDS transpose (64 rows/pass)
    float sum = 0.f, sq = 0.f;
#pragma unroll
    for (int p = 0; p < 2; ++p) {
        __syncthreads();
        if ((tid >> 6) == p) {
            float* srow = &buf[(tid & 63) * SST];
#pragma unroll
            for (int ch = 0; ch < CH; ++ch) srow[ch] = acc[ch];
        }
        __syncthreads();
        if (CH == 64) {
            int ch = tid & 63, rg = tid >> 6;
            for (int r = 0; r < 32; ++r) {
                float v = buf[(rg * 32 + r) * SST + ch];
                xout[(size_t)(rowbase + p * 64 + rg * 32 + r) * CH + ch] = v;
                sum += v; sq += v * v;
            }
        } else {
            int ch = tid & 31, rg = tid >> 5;
            for (int r = 0; r < 16; ++r) {
                float v = buf[(rg * 16 + r) * SST + ch];
                xout[(size_t)(rowbase + p * 64 + rg * 16 + r) * CH + ch] = v;
                sum += v; sq += v * v;
            }
        }
    }
    ls[tid] = sum; lq[tid] = sq;
    __syncthreads();
    if (CH == 64) {
        if (tid < 64) {
            g_psT[tid * 2048 + blockIdx.x] = ls[tid] + ls[64 + tid];
            g_pqT[tid * 2048 + blockIdx.x] = lq[tid] + lq[64 + tid];
        }
    } else {
        if (tid < 32) {
            g_psT[tid * 2048 + blockIdx.x] = ls[tid] + ls[32 + tid] + ls[64 + tid] + ls[96 + tid];
            g_pqT[tid * 2048 + blockIdx.x] = lq[tid] + lq[32 + tid] + lq[64 + tid] + lq[96 + tid];
        }
    }
}

template <int NS, int CH>
__launch_bounds__(128, 4)
__global__ void mlp_passB_kernel(const float* __restrict__ W1, const float* __restrict__ xin,
                                 float* __restrict__ xout, int bn0) {
    constexpr int HSTR = 33;
    constexpr int SST  = CH + 2;
    __shared__ float buf[128 * 37];
    __shared__ float ls[128], lq[128];
    int tid = threadIdx.x;
    int rowbase = blockIdx.x * 128;
    const float* sc0 = g_bnscale[bn0];
    const float* sh0 = g_bnshift[bn0];
    float acc2[CH];
#pragma unroll
    for (int ch = 0; ch < CH; ++ch) acc2[ch] = 0.f;
    const float4* src = (const float4*)xin;
#pragma unroll
    for (int hc = 0; hc < CH / 32; ++hc) {
        if (hc) __syncthreads();          // prior chunk readers done
        // load 32-channel chunk of all 128 rows, BN0+ReLU, h -> LDS
#pragma unroll
        for (int k = 0; k < 8; ++k) {
            int o4 = tid + k * 128;       // 0..1023
            int rloc = o4 >> 3, j = o4 & 7;
            int c = 4 * j, gc = hc * 32 + c;
            float4 v = src[(size_t)(rowbase + rloc) * (CH / 4) + hc * 8 + j];
            float* d = &buf[rloc * HSTR + c];
            d[0] = fmaxf(fmaf(v.x, sc0[gc + 0], sh0[gc + 0]), 0.f);
            d[1] = fmaxf(fmaf(v.y, sc0[gc + 1], sh0[gc + 1]), 0.f);
            d[2] = fmaxf(fmaf(v.z, sc0[gc + 2], sh0[gc + 2]), 0.f);
            d[3] = fmaxf(fmaf(v.w, sc0[gc + 3], sh0[gc + 3]), 0.f);
        }
        __syncthreads();
        const float* hrow = &buf[tid * HSTR];
        for (int c = 0; c < 32; ++c) {
            float h = hrow[c];
#pragma unroll
            for (int ch = 0; ch < CH; ++ch)
                acc2[ch] = fmaf(h, W1[(hc * 32 + c) * CH + ch], acc2[ch]);
        }
    }
    // stats + coalesced store
    float sum = 0.f, sq = 0.f;
#pragma unroll
    for (int p = 0; p < 2; ++p) {
        __syncthreads();
        if ((tid >> 6) == p) {
            float* srow = &buf[(tid & 63) * SST];
#pragma unroll
            for (int ch = 0; ch < CH; ++ch) srow[ch] = acc2[ch];
        }
        __syncthreads();
        if (CH == 64) {
            int ch = tid & 63, rg = tid >> 6;
            for (int r = 0; r < 32; ++r) {
                float v = buf[(rg * 32 + r) * SST + ch];
                xout[(size_t)(rowbase + p * 64 + rg * 32 + r) * CH + ch] = v;
                sum += v; sq += v * v;
            }
        } else {
            int ch = tid & 31, rg = tid >> 5;
            for (int r = 0; r < 16; ++r) {
                float v = buf[(rg * 16 + r) * SST + ch];
                xout[(size_t)(rowbase + p * 64 + rg * 16 + r) * CH + ch] = v;
                sum += v; sq += v * v;
            }
        }
    }
    ls[tid] = sum; lq[tid] = sq;
    __syncthreads();
    if (CH == 64) {
        if (tid < 64) {
            g_psT[tid * 2048 + blockIdx.x] = ls[tid] + ls[64 + tid];
            g_pqT[tid * 2048 + blockIdx.x] = lq[tid] + lq[64 + tid];
        }
    } else {
        if (tid < 32) {
            g_psT[tid * 2048 + blockIdx.x] = ls[tid] + ls[32 + tid] + ls[64 + tid] + ls[96 + tid];
            g_pqT[tid * 2048 + blockIdx.x] = lq[tid] + lq[32 + tid] + lq[64 + tid] + lq[96 + tid];
        }
    }
}

// PASS C deform: stream x1f, BN1+ReLU, sigmoid weight, max over 32 -> out
__global__ void passC_f_kernel(const float* __restrict__ xyz, const float* __restrict__ newxyz,
                               const float* __restrict__ td, const float* __restrict__ xin,
                               float* __restrict__ out) {
    __shared__ float lw[64];
    int tid = threadIdx.x;
    int qpair = blockIdx.x * 2;
    if (tid < 64) {
        int ql = tid >> 5, s = tid & 31;
        int q = qpair + ql;
        float wv = 0.f;
        if (!g_empty_d[q]) {
            int idx = g_idx_d[q * SD + s];
            int b = q >> 12;
            float dx = xyz[(size_t)b * NPTS * 3 + idx * 3 + 0] - newxyz[q * 3 + 0];
            float dy = xyz[(size_t)b * NPTS * 3 + idx * 3 + 1] - newxyz[q * 3 + 1];
            float dz = xyz[(size_t)b * NPTS * 3 + idx * 3 + 2] - newxyz[q * 3 + 2];
            float dist = sqrtf(dx * dx + dy * dy + dz * dz);
            float rq = g_rroi[q >> 6];
            wv = 1.f / (1.f + expf(-(rq - dist) / td[0]));
        }
        lw[tid] = wv;
    }
    __syncthreads();
    int ql = tid >> 6, ch = tid & 63;
    int q = qpair + ql;
    float sc = g_bnscale[3][ch], sh = g_bnshift[3][ch];
    float m = 0.f;
    for (int s = 0; s < SD; ++s) {
        float v = xin[((size_t)q * SD + s) * CF + ch];
        m = fmaxf(m, lw[ql * 32 + s] * fmaxf(fmaf(v, sc, sh), 0.f));
    }
    out[MTOT * 3 + (size_t)q * CF + ch] = m;
}

// PASS C pred: stream x1p, BN1+ReLU, max over 16, dot with fcw -> g_pdot
__global__ void passC_p_kernel(const float* __restrict__ fcw, const float* __restrict__ xin) {
    int tid = threadIdx.x;
    int q = blockIdx.x * 8 + (tid >> 5);
    int ch = tid & 31;
    float sc = g_bnscale[1][ch], sh = g_bnshift[1][ch];
    float m = 0.f;
    for (int s = 0; s < SP; ++s) {
        float v = xin[(size_t)(q * SP + s) * CP + ch] * sc + sh;
        m = fmaxf(m, fmaxf(v, 0.f));
    }
    float pd = m * fcw[(q & 63) * CP + ch];
    for (int off = 16; off > 0; off >>= 1) pd += __shfl_down(pd, off, 32);
    if (ch == 0) g_pdot[q] = pd;
}

// -------- BN stats finalize: one block per channel, coalesced, tree-reduce --
__global__ void finalize_kernel(const float* __restrict__ gamma, const float* __restrict__ beta,
                                float n, int layer, int nblocks) {
    __shared__ double l_s[256], l_q[256];
    int ch = blockIdx.x, tid = threadIdx.x;
    double s = 0, q = 0;
    for (int i = tid; i < nblocks; i += 256) { s += g_psT[ch * 2048 + i]; q += g_pqT[ch * 2048 + i]; }
    l_s[tid] = s; l_q[tid] = q; __syncthreads();
    for (int off = 128; off > 0; off >>= 1) {
        if (tid < off) { l_s[tid] += l_s[tid + off]; l_q[tid] += l_q[tid + off]; }
        __syncthreads();
    }
    if (tid == 0) {
        double mu = l_s[0] / (double)n;
        double var = l_q[0] / (double)n - mu * mu;
        if (var < 0) var = 0;
        double sc = (double)gamma[ch] / sqrt(var + 1e-5);
        g_bnscale[layer][ch] = (float)sc;
        g_bnshift[layer][ch] = (float)((double)beta[ch] - mu * sc);
    }
}

// ---------------- per-roi fc reduce -> deform radius -----------------------
__global__ void roi_r_kernel(const float* __restrict__ roif, const float* __restrict__ fcw,
                             const float* __restrict__ fcb) {
    int tid = threadIdx.x;
    int roi = blockIdx.x * 4 + (tid >> 6);
    int lane = tid & 63;
    float acc = g_pdot[roi * 64 + lane]
              + roif[roi * 128 + lane]      * fcw[2048 + lane]
              + roif[roi * 128 + 64 + lane] * fcw[2048 + 64 + lane];
    for (int off = 32; off > 0; off >>= 1) acc += __shfl_down(acc, off, 64);
    if (lane == 0) {
        float res = acc + fcb[0];
        g_rroi[roi] = fmaxf(res / DIV_COEF_C + RADIUS_C, MIN_R_C);
    }
}

extern "C" void kernel_launch(void* const* d_in, const int* in_sizes, int n_in,
                              void* d_out, int out_size, void* d_ws, size_t ws_size,
                              hipStream_t stream) {
    const float* xyz   = (const float*)d_in[0];
    const float* feats = (const float*)d_in[1];
    const float* rois  = (const float*)d_in[2];
    const float* roif  = (const float*)d_in[3];
    const float* td    = (const float*)d_in[4];
    const float* pw0 = (const float*)d_in[5];
    const float* pg0 = (const float*)d_in[6];
    const float* pb0 = (const float*)d_in[7];
    const float* pw1 = (const float*)d_in[8];
    const float* pg1 = (const float*)d_in[9];
    const float* pb1 = (const float*)d_in[10];
    const float* fw0 = (const float*)d_in[11];
    const float* fg0 = (const float*)d_in[12];
    const float* fb0 = (const float*)d_in[13];
    const float* fw1 = (const float*)d_in[14];
    const float* fg1 = (const float*)d_in[15];
    const float* fb1 = (const float*)d_in[16];
    const float* fcw = (const float*)d_in[17];
    const float* fcb = (const float*)d_in[18];
    float* out = (float*)d_out;

    float* xa; hipGetSymbolAddress((void**)&xa, HIP_SYMBOL(g_xa));
    float* xb; hipGetSymbolAddress((void**)&xb, HIP_SYMBOL(g_xb));

    copy_xyz_kernel<<<96, 256, 0, stream>>>(rois, out);

    // pred branch (16 samples, 32 ch)
    bq_kernel<SP><<<MTOT / 4, 256, 0, stream>>>(xyz, rois);
    mlp_passA_kernel<SP, CP><<<1024, 128, 0, stream>>>(xyz, feats, rois, pw0, xa);
    finalize_kernel<<<CP, 256, 0, stream>>>(pg0, pb0, (float)(MTOT * SP), 0, 1024);
    mlp_passB_kernel<SP, CP><<<1024, 128, 0, stream>>>(pw1, xa, xb, 0);
    finalize_kernel<<<CP, 256, 0, stream>>>(pg1, pb1, (float)(MTOT * SP), 1, 1024);
    passC_p_kernel<<<MTOT / 8, 256, 0, stream>>>(fcw, xb);
    roi_r_kernel<<<NROI / 4, 256, 0, stream>>>(roif, fcw, fcb);

    // deform branch (32 samples, 64 ch)
    bq_kernel<SD><<<MTOT / 4, 256, 0, stream>>>(xyz, rois);
    mlp_passA_kernel<SD, CF><<<2048, 128, 0, stream>>>(xyz, feats, rois, fw0, xa);
    finalize_kernel<<<CF, 256, 0, stream>>>(fg0, fb0, (float)(MTOT * SD), 2, 2048);
    mlp_passB_kernel<SD, CF><<<2048, 128, 0, stream>>>(fw1, xa, xb, 2);
    finalize_kernel<<<CF, 256, 0, stream>>>(fg1, fb1, (float)(MTOT * SD), 3, 2048);
    passC_f_kernel<<<MTOT / 2, 128, 0, stream>>>(xyz, rois, td, xb, out);
}

// Round 3
// 305.312 us; speedup vs baseline: 1.1353x; 1.0140x over previous
//
#include <hip/hip_runtime.h>
#include <hip/hip_fp16.h>

#define NB 2
#define NPTS 8192
#define NQ 4096
#define MTOT 8192      // NB*NQ
#define SP 16
#define SD 32
#define CIN 32
#define CP 32
#define CF 64
#define NROI 128       // NB*64
#define RADIUS_C 0.8f
#define MIN_R_C 0.01f
#define DIV_COEF_C 10.0f
#define TILE 512       // bq staging tile (points)

// ---------------- device-global scratch (fully rewritten every call) -------
__device__ int   g_idx_p[MTOT * SP];
__device__ int   g_empty_p[MTOT];
__device__ int   g_idx_d[MTOT * SD];
__device__ int   g_empty_d[MTOT];
// generic activation buffers: p-branch uses fp32 (16.7MB), f-branch fp16 (33.5MB)
__device__ unsigned char g_xa[(size_t)MTOT * SD * CF * 2];
__device__ unsigned char g_xb[(size_t)MTOT * SD * CF * 2];
__device__ float g_psT[CF * 2048];                // transposed: [ch][block]
__device__ float g_pqT[CF * 2048];
__device__ float g_bnscale[4][CF];                // 0=p0 1=p1 2=f0 3=f1
__device__ float g_bnshift[4][CF];
__device__ float g_pdot[MTOT];
__device__ float g_rroi[NROI];

// ---------------- new_xyz output is rois flattened -------------------------
__global__ void copy_xyz_kernel(const float* __restrict__ rois, float* __restrict__ out) {
    int i = blockIdx.x * 256 + threadIdx.x;
    if (i < MTOT * 3) out[i] = rois[i];
}

// ------- ball query: 4 queries/block (1 per wave), 512-pt LDS tiles --------
// staging coalesced float4 shared by 4 queries; distance tests from LDS
// (stride-3 float reads: 2-way bank alias = free). 6.2 KB LDS -> 32 waves/CU.
template <int NS>
__launch_bounds__(256, 8)
__global__ void bq_kernel(const float* __restrict__ xyz, const float* __restrict__ newxyz) {
    __shared__ float4 l4[TILE * 3 / 4];   // 6 KB
    __shared__ int s_active;
    int tid = threadIdx.x;
    int wave = tid >> 6, lane = tid & 63;
    int q = blockIdx.x * 4 + wave;        // 4 consecutive q -> same batch
    int b = q >> 12;
    const float4* xb4 = (const float4*)(xyz + (size_t)b * NPTS * 3);
    const float* lp = (const float*)l4;
    float qx = newxyz[q * 3 + 0], qy = newxyz[q * 3 + 1], qz = newxyz[q * 3 + 2];
    float r = (NS == SP) ? RADIUS_C : g_rroi[q >> 6];
    float r2 = r * r;
    int* idx_out   = (NS == SP) ? g_idx_p   : g_idx_d;
    int* empty_out = (NS == SP) ? g_empty_p : g_empty_d;

    int cnt = 0, first_idx = 0;
    for (int t = 0; t < NPTS / TILE; ++t) {
        l4[tid] = xb4[t * 384 + tid];                       // 256
        if (tid + 256 < 384) l4[tid + 256] = xb4[t * 384 + tid + 256];  // +128
        if (tid == 0) s_active = 0;
        __syncthreads();
        if (cnt < NS) {
            for (int s = 0; s < TILE / 64; ++s) {
                int pl = s * 64 + lane;
                float dx = qx - lp[3 * pl + 0];
                float dy = qy - lp[3 * pl + 1];
                float dz = qz - lp[3 * pl + 2];
                bool valid = (dx * dx + dy * dy + dz * dz) < r2;
                unsigned long long mask = __ballot(valid);
                if (cnt == 0 && mask) first_idx = t * TILE + s * 64 + (int)__builtin_ctzll(mask);
                int pos = cnt + __popcll(mask & ((1ull << lane) - 1ull));
                if (valid && pos < NS) idx_out[q * NS + pos] = t * TILE + s * 64 + lane;
                cnt += __popcll(mask);
                if (cnt >= NS) break;
            }
            if (cnt < NS && lane == 0) s_active = 1;
        }
        __syncthreads();
        if (!s_active) break;
    }
    if (cnt == 0) {
        if (lane < NS) idx_out[q * NS + lane] = 0;
        if (lane == 0) empty_out[q] = 1;
    } else {
        int filled = cnt < NS ? cnt : NS;
        if (lane >= filled && lane < NS) idx_out[q * NS + lane] = first_idx;
        if (lane == 0) empty_out[q] = 0;
    }
}

// ============ 3-pass MLP =====================================================
// PASS A: gather -> L0 -> store x0 (fp32 for p-branch, fp16 for f-branch) + stats
// block = 128 threads (2 waves), LDS <= 19.5 KB.
template <int NS, int CH, bool HALF>
__launch_bounds__(128, 4)
__global__ void mlp_passA_kernel(const float* __restrict__ xyz, const float* __restrict__ feats,
                                 const float* __restrict__ newxyz, const float* __restrict__ W0,
                                 void* __restrict__ xout_) {
    constexpr int GSTR = 37;        // gather row stride (35 used)
    constexpr int SST  = CH + 2;    // stats/store transpose stride
    __shared__ float buf[128 * GSTR];
    __shared__ float ls[128], lq[128];
    int tid = threadIdx.x;
    int rowbase = blockIdx.x * 128;
    int row = rowbase + tid;
    int q = row / NS, b = q >> 12;
    const int* idx_arr = (NS == SP) ? g_idx_p : g_idx_d;
    const int* emp_arr = (NS == SP) ? g_empty_p : g_empty_d;
    {
        float* dst = &buf[tid * GSTR];
        if (emp_arr[q]) {
#pragma unroll
            for (int c = 0; c < 35; ++c) dst[c] = 0.f;
        } else {
            int idx = idx_arr[row];
            const float* xp = xyz + (size_t)b * NPTS * 3 + idx * 3;
            dst[0] = xp[0] - newxyz[q * 3 + 0];
            dst[1] = xp[1] - newxyz[q * 3 + 1];
            dst[2] = xp[2] - newxyz[q * 3 + 2];
            const float4* fp = (const float4*)(feats + (size_t)b * NPTS * CIN + (size_t)idx * CIN);
#pragma unroll
            for (int j = 0; j < 8; ++j) {
                float4 v = fp[j];
                dst[3 + 4 * j + 0] = v.x; dst[3 + 4 * j + 1] = v.y;
                dst[3 + 4 * j + 2] = v.z; dst[3 + 4 * j + 3] = v.w;
            }
        }
    }
    // L0 from own LDS row (no barrier needed)
    float acc[CH];
#pragma unroll
    for (int ch = 0; ch < CH; ++ch) acc[ch] = 0.f;
    {
        const float* inrow = &buf[tid * GSTR];
        for (int c = 0; c < 35; ++c) {
            float h = inrow[c];
#pragma unroll
            for (int ch = 0; ch < CH; ++ch) acc[ch] = fmaf(h, W0[c * CH + ch], acc[ch]);
        }
    }
    // stats (fp32, pre-rounding) + coalesced store via chunked LDS transpose
    float* xf = (float*)xout_;
    __half* xh = (__half*)xout_;
    float sum = 0.f, sq = 0.f;
#pragma unroll
    for (int p = 0; p < 2; ++p) {
        __syncthreads();
        if ((tid >> 6) == p) {
            float* srow = &buf[(tid & 63) * SST];
#pragma unroll
            for (int ch = 0; ch < CH; ++ch) srow[ch] = acc[ch];
        }
        __syncthreads();
        if (CH == 64) {
            int ch = tid & 63, rg = tid >> 6;
            for (int r = 0; r < 32; ++r) {
                float v = buf[(rg * 32 + r) * SST + ch];
                size_t o = (size_t)(rowbase + p * 64 + rg * 32 + r) * CH + ch;
                if (HALF) xh[o] = __float2half_rn(v); else xf[o] = v;
                sum += v; sq += v * v;
            }
        } else {
            int ch = tid & 31, rg = tid >> 5;
            for (int r = 0; r < 16; ++r) {
                float v = buf[(rg * 16 + r) * SST + ch];
                size_t o = (size_t)(rowbase + p * 64 + rg * 16 + r) * CH + ch;
                if (HALF) xh[o] = __float2half_rn(v); else xf[o] = v;
                sum += v; sq += v * v;
            }
        }
    }
    ls[tid] = sum; lq[tid] = sq;
    __syncthreads();
    if (CH == 64) {
        if (tid < 64) {
            g_psT[tid * 2048 + blockIdx.x] = ls[tid] + ls[64 + tid];
            g_pqT[tid * 2048 + blockIdx.x] = lq[tid] + lq[64 + tid];
        }
    } else {
        if (tid < 32) {
            g_psT[tid * 2048 + blockIdx.x] = ls[tid] + ls[32 + tid] + ls[64 + tid] + ls[96 + tid];
            g_pqT[tid * 2048 + blockIdx.x] = lq[tid] + lq[32 + tid] + lq[64 + tid] + lq[96 + tid];
        }
    }
}

// PASS B (p-branch, fp32): stream x0p -> BN0+ReLU -> L1 -> store x1p + stats
template <int NS, int CH>
__launch_bounds__(128, 4)
__global__ void mlp_passB_kernel(const float* __restrict__ W1, const float* __restrict__ xin,
                                 float* __restrict__ xout, int bn0) {
    constexpr int HSTR = 33;
    constexpr int SST  = CH + 2;
    __shared__ float buf[128 * 37];
    __shared__ float ls[128], lq[128];
    int tid = threadIdx.x;
    int rowbase = blockIdx.x * 128;
    const float* sc0 = g_bnscale[bn0];
    const float* sh0 = g_bnshift[bn0];
    float acc2[CH];
#pragma unroll
    for (int ch = 0; ch < CH; ++ch) acc2[ch] = 0.f;
    const float4* src = (const float4*)xin;
#pragma unroll
    for (int hc = 0; hc < CH / 32; ++hc) {
        if (hc) __syncthreads();
#pragma unroll
        for (int k = 0; k < 8; ++k) {
            int o4 = tid + k * 128;       // 0..1023
            int rloc = o4 >> 3, j = o4 & 7;
            int c = 4 * j, gc = hc * 32 + c;
            float4 v = src[(size_t)(rowbase + rloc) * (CH / 4) + hc * 8 + j];
            float* d = &buf[rloc * HSTR + c];
            d[0] = fmaxf(fmaf(v.x, sc0[gc + 0], sh0[gc + 0]), 0.f);
            d[1] = fmaxf(fmaf(v.y, sc0[gc + 1], sh0[gc + 1]), 0.f);
            d[2] = fmaxf(fmaf(v.z, sc0[gc + 2], sh0[gc + 2]), 0.f);
            d[3] = fmaxf(fmaf(v.w, sc0[gc + 3], sh0[gc + 3]), 0.f);
        }
        __syncthreads();
        const float* hrow = &buf[tid * HSTR];
        for (int c = 0; c < 32; ++c) {
            float h = hrow[c];
#pragma unroll
            for (int ch = 0; ch < CH; ++ch)
                acc2[ch] = fmaf(h, W1[(hc * 32 + c) * CH + ch], acc2[ch]);
        }
    }
    float sum = 0.f, sq = 0.f;
#pragma unroll
    for (int p = 0; p < 2; ++p) {
        __syncthreads();
        if ((tid >> 6) == p) {
            float* srow = &buf[(tid & 63) * SST];
#pragma unroll
            for (int ch = 0; ch < CH; ++ch) srow[ch] = acc2[ch];
        }
        __syncthreads();
        int ch = tid & 31, rg = tid >> 5;
        for (int r = 0; r < 16; ++r) {
            float v = buf[(rg * 16 + r) * SST + ch];
            xout[(size_t)(rowbase + p * 64 + rg * 16 + r) * CH + ch] = v;
            sum += v; sq += v * v;
        }
    }
    ls[tid] = sum; lq[tid] = sq;
    __syncthreads();
    if (tid < 32) {
        g_psT[tid * 2048 + blockIdx.x] = ls[tid] + ls[32 + tid] + ls[64 + tid] + ls[96 + tid];
        g_pqT[tid * 2048 + blockIdx.x] = lq[tid] + lq[32 + tid] + lq[64 + tid] + lq[96 + tid];
    }
}

// PASS B (f-branch, fp16 in/out): one coalesced full-row load phase into
// padded-LDS halves (stride 66), then pure FMA, then transpose-store + stats.
__launch_bounds__(128, 4)
__global__ void mlp_fB_kernel(const float* __restrict__ W1, const __half* __restrict__ xin,
                              __half* __restrict__ xout) {
    __shared__ float fbuf[64 * 66];       // 16.9 KB; half-view: 128 rows x 66 halves
    __shared__ float ls[128], lq[128];
    __half* hbuf = (__half*)fbuf;
    unsigned int* w32 = (unsigned int*)fbuf;
    int tid = threadIdx.x;
    int rowbase = blockIdx.x * 128;
    // load: 128 rows x 128 B = 1024 float4, fully coalesced; scatter to padded rows
    {
        const float4* src = (const float4*)xin;
#pragma unroll
        for (int k = 0; k < 8; ++k) {
            int o4 = tid + k * 128;       // 0..1023
            int rloc = o4 >> 3, j = o4 & 7;
            float4 v = src[(size_t)(rowbase + rloc) * 8 + j];
            const unsigned int* s32 = (const unsigned int*)&v;
#pragma unroll
            for (int m = 0; m < 4; ++m) w32[rloc * 33 + 4 * j + m] = s32[m];
        }
    }
    __syncthreads();
    const float* sc0 = g_bnscale[2];
    const float* sh0 = g_bnshift[2];
    float acc2[CF];
#pragma unroll
    for (int ch = 0; ch < CF; ++ch) acc2[ch] = 0.f;
    {
        const __half* hrow = &hbuf[tid * 66];
        for (int c = 0; c < 64; ++c) {
            float h = fmaxf(fmaf(__half2float(hrow[c]), sc0[c], sh0[c]), 0.f);
#pragma unroll
            for (int ch = 0; ch < CF; ++ch)
                acc2[ch] = fmaf(h, W1[c * CF + ch], acc2[ch]);
        }
    }
    // stats (fp32) + coalesced half store via transpose staging (stride 66)
    float sum = 0.f, sq = 0.f;
#pragma unroll
    for (int p = 0; p < 2; ++p) {
        __syncthreads();
        if ((tid >> 6) == p) {
            float* srow = &fbuf[(tid & 63) * 66];
#pragma unroll
            for (int ch = 0; ch < CF; ++ch) srow[ch] = acc2[ch];
        }
        __syncthreads();
        int ch = tid & 63, rg = tid >> 6;
        for (int r = 0; r < 32; ++r) {
            float v = fbuf[(rg * 32 + r) * 66 + ch];
            xout[(size_t)(rowbase + p * 64 + rg * 32 + r) * CF + ch] = __float2half_rn(v);
            sum += v; sq += v * v;
        }
    }
    ls[tid] = sum; lq[tid] = sq;
    __syncthreads();
    if (tid < 64) {
        g_psT[tid * 2048 + blockIdx.x] = ls[tid] + ls[64 + tid];
        g_pqT[tid * 2048 + blockIdx.x] = lq[tid] + lq[64 + tid];
    }
}

// PASS C deform: stream x1f (fp16), BN1+ReLU, sigmoid weight, max over 32 -> out
__global__ void passC_f_kernel(const float* __restrict__ xyz, const float* __restrict__ newxyz,
                               const float* __restrict__ td, const __half* __restrict__ xin,
                               float* __restrict__ out) {
    __shared__ float lw[64];
    int tid = threadIdx.x;
    int qpair = blockIdx.x * 2;
    if (tid < 64) {
        int ql = tid >> 5, s = tid & 31;
        int q = qpair + ql;
        float wv = 0.f;
        if (!g_empty_d[q]) {
            int idx = g_idx_d[q * SD + s];
            int b = q >> 12;
            float dx = xyz[(size_t)b * NPTS * 3 + idx * 3 + 0] - newxyz[q * 3 + 0];
            float dy = xyz[(size_t)b * NPTS * 3 + idx * 3 + 1] - newxyz[q * 3 + 1];
            float dz = xyz[(size_t)b * NPTS * 3 + idx * 3 + 2] - newxyz[q * 3 + 2];
            float dist = sqrtf(dx * dx + dy * dy + dz * dz);
            float rq = g_rroi[q >> 6];
            wv = 1.f / (1.f + expf(-(rq - dist) / td[0]));
        }
        lw[tid] = wv;
    }
    __syncthreads();
    int ql = tid >> 6, ch = tid & 63;
    int q = qpair + ql;
    float sc = g_bnscale[3][ch], sh = g_bnshift[3][ch];
    float m = 0.f;
    for (int s = 0; s < SD; ++s) {
        float v = __half2float(xin[((size_t)q * SD + s) * CF + ch]);
        m = fmaxf(m, lw[ql * 32 + s] * fmaxf(fmaf(v, sc, sh), 0.f));
    }
    out[MTOT * 3 + (size_t)q * CF + ch] = m;
}

// PASS C pred (fp32): stream x1p, BN1+ReLU, max over 16, dot with fcw -> g_pdot
__global__ void passC_p_kernel(const float* __restrict__ fcw, const float* __restrict__ xin) {
    int tid = threadIdx.x;
    int q = blockIdx.x * 8 + (tid >> 5);
    int ch = tid & 31;
    float sc = g_bnscale[1][ch], sh = g_bnshift[1][ch];
    float m = 0.f;
    for (int s = 0; s < SP; ++s) {
        float v = xin[(size_t)(q * SP + s) * CP + ch] * sc + sh;
        m = fmaxf(m, fmaxf(v, 0.f));
    }
    float pd = m * fcw[(q & 63) * CP + ch];
    for (int off = 16; off > 0; off >>= 1) pd += __shfl_down(pd, off, 32);
    if (ch == 0) g_pdot[q] = pd;
}

// -------- BN stats finalize: one block per channel, coalesced, tree-reduce --
__global__ void finalize_kernel(const float* __restrict__ gamma, const float* __restrict__ beta,
                                float n, int layer, int nblocks) {
    __shared__ double l_s[256], l_q[256];
    int ch = blockIdx.x, tid = threadIdx.x;
    double s = 0, q = 0;
    for (int i = tid; i < nblocks; i += 256) { s += g_psT[ch * 2048 + i]; q += g_pqT[ch * 2048 + i]; }
    l_s[tid] = s; l_q[tid] = q; __syncthreads();
    for (int off = 128; off > 0; off >>= 1) {
        if (tid < off) { l_s[tid] += l_s[tid + off]; l_q[tid] += l_q[tid + off]; }
        __syncthreads();
    }
    if (tid == 0) {
        double mu = l_s[0] / (double)n;
        double var = l_q[0] / (double)n - mu * mu;
        if (var < 0) var = 0;
        double sc = (double)gamma[ch] / sqrt(var + 1e-5);
        g_bnscale[layer][ch] = (float)sc;
        g_bnshift[layer][ch] = (float)((double)beta[ch] - mu * sc);
    }
}

// ---------------- per-roi fc reduce -> deform radius -----------------------
__global__ void roi_r_kernel(const float* __restrict__ roif, const float* __restrict__ fcw,
                             const float* __restrict__ fcb) {
    int tid = threadIdx.x;
    int roi = blockIdx.x * 4 + (tid >> 6);
    int lane = tid & 63;
    float acc = g_pdot[roi * 64 + lane]
              + roif[roi * 128 + lane]      * fcw[2048 + lane]
              + roif[roi * 128 + 64 + lane] * fcw[2048 + 64 + lane];
    for (int off = 32; off > 0; off >>= 1) acc += __shfl_down(acc, off, 64);
    if (lane == 0) {
        float res = acc + fcb[0];
        g_rroi[roi] = fmaxf(res / DIV_COEF_C + RADIUS_C, MIN_R_C);
    }
}

extern "C" void kernel_launch(void* const* d_in, const int* in_sizes, int n_in,
                              void* d_out, int out_size, void* d_ws, size_t ws_size,
                              hipStream_t stream) {
    const float* xyz   = (const float*)d_in[0];
    const float* feats = (const float*)d_in[1];
    const float* rois  = (const float*)d_in[2];
    const float* roif  = (const float*)d_in[3];
    const float* td    = (const float*)d_in[4];
    const float* pw0 = (const float*)d_in[5];
    const float* pg0 = (const float*)d_in[6];
    const float* pb0 = (const float*)d_in[7];
    const float* pw1 = (const float*)d_in[8];
    const float* pg1 = (const float*)d_in[9];
    const float* pb1 = (const float*)d_in[10];
    const float* fw0 = (const float*)d_in[11];
    const float* fg0 = (const float*)d_in[12];
    const float* fb0 = (const float*)d_in[13];
    const float* fw1 = (const float*)d_in[14];
    const float* fg1 = (const float*)d_in[15];
    const float* fb1 = (const float*)d_in[16];
    const float* fcw = (const float*)d_in[17];
    const float* fcb = (const float*)d_in[18];
    float* out = (float*)d_out;

    void* xa; hipGetSymbolAddress(&xa, HIP_SYMBOL(g_xa));
    void* xb; hipGetSymbolAddress(&xb, HIP_SYMBOL(g_xb));

    copy_xyz_kernel<<<96, 256, 0, stream>>>(rois, out);

    // pred branch (16 samples, 32 ch, all fp32 -> radii bit-identical)
    bq_kernel<SP><<<MTOT / 4, 256, 0, stream>>>(xyz, rois);
    mlp_passA_kernel<SP, CP, false><<<1024, 128, 0, stream>>>(xyz, feats, rois, pw0, xa);
    finalize_kernel<<<CP, 256, 0, stream>>>(pg0, pb0, (float)(MTOT * SP), 0, 1024);
    mlp_passB_kernel<SP, CP><<<1024, 128, 0, stream>>>(pw1, (const float*)xa, (float*)xb, 0);
    finalize_kernel<<<CP, 256, 0, stream>>>(pg1, pb1, (float)(MTOT * SP), 1, 1024);
    passC_p_kernel<<<MTOT / 8, 256, 0, stream>>>(fcw, (const float*)xb);
    roi_r_kernel<<<NROI / 4, 256, 0, stream>>>(roif, fcw, fcb);

    // deform branch (32 samples, 64 ch, fp16 intermediates)
    bq_kernel<SD><<<MTOT / 4, 256, 0, stream>>>(xyz, rois);
    mlp_passA_kernel<SD, CF, true><<<2048, 128, 0, stream>>>(xyz, feats, rois, fw0, xa);
    finalize_kernel<<<CF, 256, 0, stream>>>(fg0, fb0, (float)(MTOT * SD), 2, 2048);
    mlp_fB_kernel<<<2048, 128, 0, stream>>>(fw1, (const __half*)xa, (__half*)xb);
    finalize_kernel<<<CF, 256, 0, stream>>>(fg1, fb1, (float)(MTOT * SD), 3, 2048);
    passC_f_kernel<<<MTOT / 2, 128, 0, stream>>>(xyz, rois, td, (const __half*)xb, out);
}